// Round 14
// baseline (4294.543 us; speedup 1.0000x reference)
//
#include <hip/hip_runtime.h>
#include <hip/hip_bf16.h>

typedef __attribute__((ext_vector_type(8)))  short short8;
typedef __attribute__((ext_vector_type(4)))  float f32x4;
typedef __attribute__((ext_vector_type(4)))  unsigned int uint4v;

#define TSTEPS 1024
#define BATCH  128
#define NIN    256
#define NHID   512
#define NBLK   128

// ws layout (zeroed each launch):
#define DATA0   0         // 8 groups x 2 slots x 16KB h-fragment data
#define TAGS0   262144    // 8 groups x 64 tags x 64B
#define ZBYTES  294912
#define XB2OFF  (1 << 20) // 64MB bf16 fragment-layout x

static __device__ __forceinline__ unsigned short f2bf(float f) {
  unsigned int u = __builtin_bit_cast(unsigned int, f);
  u += 0x7fffu + ((u >> 16) & 1u);
  return (unsigned short)(u >> 16);
}

static __device__ __forceinline__ unsigned long long pack4(float a, float b, float c, float d) {
  return (unsigned long long)f2bf(a)
       | ((unsigned long long)f2bf(b) << 16)
       | ((unsigned long long)f2bf(c) << 32)
       | ((unsigned long long)f2bf(d) << 48);
}

static __device__ __forceinline__ short8 packb(const float* p) {
  float4 f0 = *(const float4*)p;
  float4 f1 = *(const float4*)(p + 4);
  unsigned long long lo = pack4(f0.x, f0.y, f0.z, f0.w);
  unsigned long long hi = pack4(f1.x, f1.y, f1.z, f1.w);
  uint4v u;
  u.x = (unsigned int)lo; u.y = (unsigned int)(lo >> 32);
  u.z = (unsigned int)hi; u.w = (unsigned int)(hi >> 32);
  return __builtin_bit_cast(short8, u);
}

static __device__ __forceinline__ float sigf(float x) {
  return 1.0f / (1.0f + __expf(-x));
}
static __device__ __forceinline__ float tanh_fast(float x) {
  x = fminf(fmaxf(x, -15.0f), 15.0f);
  float e = __expf(2.0f * x);
  return (e - 1.0f) / (e + 1.0f);
}

// ---- LLC-coherent (sc0 sc1) memory helpers — the R5-R12-proven scope ----
static __device__ __forceinline__ uint4v ld16c(const char* p) {
  uint4v r;
  asm volatile("global_load_dwordx4 %0, %1, off sc0 sc1" : "=v"(r) : "v"(p));
  return r;
}
static __device__ __forceinline__ void st16c(char* p, uint4v v) {
  asm volatile("global_store_dwordx4 %0, %1, off sc0 sc1" :: "v"(p), "v"(v) : "memory");
}
static __device__ __forceinline__ unsigned int ld4c(const char* p) {
  unsigned int r;
  asm volatile("global_load_dword %0, %1, off sc0 sc1" : "=v"(r) : "v"(p));
  return r;
}
static __device__ __forceinline__ void st4c(char* p, unsigned int v) {
  asm volatile("global_store_dword %0, %1, off sc0 sc1" :: "v"(p), "v"(v) : "memory");
}

#define VMW0 do { asm volatile("s_waitcnt vmcnt(0)" ::: "memory"); \
  __builtin_amdgcn_sched_barrier(0); } while (0)

__global__ void init_ws_kernel(unsigned long long* w) {
  int idx = blockIdx.x * blockDim.x + threadIdx.x;
  for (int i = idx; i < ZBYTES / 8; i += 16384) w[i] = 0ull;
}

// x fp32 -> bf16 A-fragment layout: 16B unit v = ((t*8+kb)*128+m)*4 + ku
// holds x[t][m][kb*32 + ku*8 + 0..7]
__global__ void convert_x_kernel(const float* __restrict__ x, char* __restrict__ xb2) {
  const int NU = TSTEPS * 8 * BATCH * 4;
  for (int v = blockIdx.x * blockDim.x + threadIdx.x; v < NU; v += gridDim.x * blockDim.x) {
    int t = v >> 12;
    int rem = v & 4095;
    int kb = rem >> 9;
    int m  = (rem >> 2) & 127;
    int ku = rem & 3;
    const float* s = x + (((size_t)t * BATCH + m) << 8) + kb * 32 + ku * 8;
    short8 b = packb(s);
    *(uint4v*)(xb2 + (size_t)v * 16) = __builtin_bit_cast(uint4v, b);
  }
}

#define MM(xr, k) do { short8 A_ = __builtin_bit_cast(short8, xr); \
    acc0 = __builtin_amdgcn_mfma_f32_16x16x32_bf16(A_, bfrag[k][0], acc0, 0, 0, 0); \
    acc1 = __builtin_amdgcn_mfma_f32_16x16x32_bf16(A_, bfrag[k][1], acc1, 0, 0, 0); } while (0)

template <int USE_BF>
__global__ __launch_bounds__(256, 1) void lstm_persistent(
    const float* __restrict__ x,
    const char* __restrict__ xb2,
    const float* __restrict__ Wih,
    const float* __restrict__ Whh,
    const float* __restrict__ bih,
    const float* __restrict__ bhh,
    float* __restrict__ out,
    char* __restrict__ ws)
{
  const int tid  = threadIdx.x;
  const int lane = tid & 63;
  const int wv   = tid >> 6;
  const int bid  = blockIdx.x;
  const int n    = lane & 15;   // tile col
  const int q    = lane >> 4;   // k-subgroup / row-quad

  // group gm = batch rows [16gm,+16); col slot s = hcols [32s,+32).
  // bid&7 aligns group members on one XCD under round-robin dispatch (L2 locality
  // for x reads only; exchange goes through LLC).
  const int gm = bid & 7;
  const int s  = bid >> 3;

  __shared__ __attribute__((aligned(16))) short hstage[512];  // per-wave 16x8 transpose

  // ---------------- W fragments (16x16x32 B-operand) + bias ----------------
  // wave covers hcols [32s+8wv, +8); z-cols: tile0 = gates{0,1}x8, tile1 = gates{2,3}x8
  short8 bfrag[24][2];
  float biasv[2];
#pragma unroll
  for (int tau = 0; tau < 2; ++tau) {
    int gate = tau * 2 + (n >> 3);
    int wr = gate * NHID + s * 32 + wv * 8 + (n & 7);
    biasv[tau] = bih[wr] + bhh[wr];
#pragma unroll
    for (int kt = 0; kt < 8; ++kt) {
      bfrag[kt][tau] = packb(Wih + (size_t)wr * NIN + kt * 32 + q * 8);
    }
#pragma unroll
    for (int kt = 8; kt < 24; ++kt) {
      bfrag[kt][tau] = packb(Whh + (size_t)wr * NHID + (kt - 8) * 32 + q * 8);
    }
  }

  float creg[4] = {0.0f, 0.0f, 0.0f, 0.0f};
  char* tbq = ws + TAGS0 + gm * 4096;
  int dead = 0;

#define XINIT(tt) do { if (USE_BF) { \
    const char* xb_ = xb2 + (size_t)(tt) * 65536 + gm * 1024 + n * 64 + (q << 4); \
    asm volatile("global_load_dwordx4 %0, %1, off" : "=v"(xf0) : "v"(xb_ + 0 * 8192)); \
    asm volatile("global_load_dwordx4 %0, %1, off" : "=v"(xf1) : "v"(xb_ + 1 * 8192)); \
    asm volatile("global_load_dwordx4 %0, %1, off" : "=v"(xf2) : "v"(xb_ + 2 * 8192)); \
    asm volatile("global_load_dwordx4 %0, %1, off" : "=v"(xf3) : "v"(xb_ + 3 * 8192)); \
    asm volatile("global_load_dwordx4 %0, %1, off" : "=v"(xf4) : "v"(xb_ + 4 * 8192)); \
    asm volatile("global_load_dwordx4 %0, %1, off" : "=v"(xf5) : "v"(xb_ + 5 * 8192)); \
    asm volatile("global_load_dwordx4 %0, %1, off" : "=v"(xf6) : "v"(xb_ + 6 * 8192)); \
    asm volatile("global_load_dwordx4 %0, %1, off" : "=v"(xf7) : "v"(xb_ + 7 * 8192)); \
  } else { \
    const float* xr_ = x + ((size_t)(tt) * BATCH + 16 * gm + n) * NIN + q * 8; \
    xf0 = __builtin_bit_cast(uint4v, packb(xr_ + 0)); \
    xf1 = __builtin_bit_cast(uint4v, packb(xr_ + 32)); \
    xf2 = __builtin_bit_cast(uint4v, packb(xr_ + 64)); \
    xf3 = __builtin_bit_cast(uint4v, packb(xr_ + 96)); \
    xf4 = __builtin_bit_cast(uint4v, packb(xr_ + 128)); \
    xf5 = __builtin_bit_cast(uint4v, packb(xr_ + 160)); \
    xf6 = __builtin_bit_cast(uint4v, packb(xr_ + 192)); \
    xf7 = __builtin_bit_cast(uint4v, packb(xr_ + 224)); \
  } } while (0)

  uint4v xf0, xf1, xf2, xf3, xf4, xf5, xf6, xf7;
  XINIT(0);

  for (int t = 0; t < TSTEPS; ++t) {
    // -------- 1. poll 64 per-wave tags (lane i watches tag i); sticky cap ----------
    if (!dead) {
      const char* tp = tbq + lane * 64;
      int it = 0;
      bool ok;
      do {
        unsigned int tv = ld4c(tp);
        asm volatile("s_waitcnt vmcnt(0)" ::: "memory");
        ok = __all((int)(tv >= (unsigned int)t));
      } while (!ok && ++it < (1 << 17));
      if (!ok) dead = 1;   // fail visibly (wrong output), never hang
      __builtin_amdgcn_sched_barrier(0);
    }

    // -------- 2. h fragments via LLC, 2 batches pipelined into MFMAs ---------------
    const char* hb = ws + DATA0 + gm * 32768 + (t & 1) * 16384 + n * 64 + (q << 4);
    uint4v h0 = ld16c(hb + 0 * 1024);
    uint4v h1 = ld16c(hb + 1 * 1024);
    uint4v h2 = ld16c(hb + 2 * 1024);
    uint4v h3 = ld16c(hb + 3 * 1024);
    uint4v h4 = ld16c(hb + 4 * 1024);
    uint4v h5 = ld16c(hb + 5 * 1024);
    uint4v h6 = ld16c(hb + 6 * 1024);
    uint4v h7 = ld16c(hb + 7 * 1024);

    // x MFMAs while batch A is in flight (xf regs were drained by the poll's vmcnt(0))
    f32x4 acc0 = {biasv[0], biasv[0], biasv[0], biasv[0]};
    f32x4 acc1 = {biasv[1], biasv[1], biasv[1], biasv[1]};
    MM(xf0, 0); MM(xf1, 1); MM(xf2, 2); MM(xf3, 3);
    MM(xf4, 4); MM(xf5, 5); MM(xf6, 6); MM(xf7, 7);
    VMW0;
    uint4v g0 = ld16c(hb +  8 * 1024);
    uint4v g1 = ld16c(hb +  9 * 1024);
    uint4v g2 = ld16c(hb + 10 * 1024);
    uint4v g3 = ld16c(hb + 11 * 1024);
    uint4v g4 = ld16c(hb + 12 * 1024);
    uint4v g5 = ld16c(hb + 13 * 1024);
    uint4v g6 = ld16c(hb + 14 * 1024);
    uint4v g7 = ld16c(hb + 15 * 1024);
    MM(h0, 8);  MM(h1, 9);  MM(h2, 10); MM(h3, 11);
    MM(h4, 12); MM(h5, 13); MM(h6, 14); MM(h7, 15);
    VMW0;
    MM(g0, 16); MM(g1, 17); MM(g2, 18); MM(g3, 19);
    MM(g4, 20); MM(g5, 21); MM(g6, 22); MM(g7, 23);

    // -------- 3. gates: pair-exchange (lane ^ 8) then cell update ------------------
    // C/D (16x16x32, m89): col = lane&15, row = q*4 + reg.  n<8: acc0=i, acc1=g;
    // n>=8: acc0=f, acc1=o (same hcol as partner lane^8).
    float hv[4];
    {
      float pa0[4], pa1[4];
#pragma unroll
      for (int r = 0; r < 4; ++r) {
        pa0[r] = __shfl_xor(acc0[r], 8);
        pa1[r] = __shfl_xor(acc1[r], 8);
      }
      const bool lo = ((lane & 8) == 0);
#pragma unroll
      for (int r = 0; r < 4; ++r) {
        float zi = lo ? acc0[r] : pa0[r];
        float zg = lo ? acc1[r] : pa1[r];
        float zf = lo ? pa0[r] : acc0[r];
        float zo = lo ? pa1[r] : acc1[r];
        float iv = sigf(zi);
        float fv = sigf(zf);
        float gv = tanh_fast(zg);
        float ov = sigf(zo);
        float cn = fv * creg[r] + iv * gv;
        creg[r] = cn;
        hv[r] = ov * tanh_fast(cn);
      }
    }

    if (t == TSTEPS - 1) {
      if ((lane & 8) == 0) {
#pragma unroll
        for (int r = 0; r < 4; ++r) {
          int grow = 16 * gm + q * 4 + r;
          size_t o = (size_t)grow * NHID + s * 32 + wv * 8 + n;
          out[o]          = hv[r];
          out[65536 + o]  = hv[r];
          out[131072 + o] = creg[r];
        }
      }
    } else {
      // -------- 4. publish: wave-local 16x8 LDS transpose, 16B stores, tag ---------
      if ((lane & 8) == 0) {
#pragma unroll
        for (int r = 0; r < 4; ++r) {
          hstage[wv * 128 + (q * 4 + r) * 8 + n] = (short)f2bf(hv[r]);
        }
      }
      asm volatile("s_waitcnt lgkmcnt(0)" ::: "memory");
      __builtin_amdgcn_sched_barrier(0);
      if (lane < 16) {
        uint4v hvv = *(const uint4v*)&hstage[wv * 128 + lane * 8];
        st16c(ws + DATA0 + gm * 32768 + ((t + 1) & 1) * 16384
                  + s * 1024 + lane * 64 + (wv << 4), hvv);
      }
      VMW0;   // only the h store is outstanding here
      if (lane == 0) {
        st4c(tbq + (s * 4 + wv) * 64, (unsigned int)(t + 1));
      }
    }

    // -------- 5. issue x for t+1 (plain cached loads; drained by next poll) --------
    if (t + 1 < TSTEPS) {
      XINIT(t + 1);
    }
  }
#undef XINIT
}

extern "C" void kernel_launch(void* const* d_in, const int* in_sizes, int n_in,
                              void* d_out, int out_size, void* d_ws, size_t ws_size,
                              hipStream_t stream) {
  const float* x   = (const float*)d_in[0];
  const float* Wih = (const float*)d_in[1];
  const float* Whh = (const float*)d_in[2];
  const float* bih = (const float*)d_in[3];
  const float* bhh = (const float*)d_in[4];
  float* out = (float*)d_out;

  char* ws  = (char*)d_ws;
  char* xb2 = ws + XB2OFF;

  size_t need = (size_t)XB2OFF + (size_t)TSTEPS * BATCH * NIN * 2;
  bool bf = ws_size >= need;

  hipLaunchKernelGGL(init_ws_kernel, dim3(64), dim3(256), 0, stream,
                     (unsigned long long*)ws);
  if (bf) {
    hipLaunchKernelGGL(convert_x_kernel, dim3(8192), dim3(256), 0, stream, x, xb2);
    hipLaunchKernelGGL((lstm_persistent<1>), dim3(NBLK), dim3(256), 0, stream,
                       x, xb2, Wih, Whh, bih, bhh, out, ws);
  } else {
    hipLaunchKernelGGL((lstm_persistent<0>), dim3(NBLK), dim3(256), 0, stream,
                       x, xb2, Wih, Whh, bih, bhh, out, ws);
  }
}

// Round 15
// 3382.143 us; speedup vs baseline: 1.2698x; 1.2698x over previous
//
#include <hip/hip_runtime.h>
#include <hip/hip_bf16.h>

typedef __attribute__((ext_vector_type(8)))  short short8;
typedef __attribute__((ext_vector_type(16))) float f32x16;
typedef __attribute__((ext_vector_type(4)))  unsigned int uint4v;

#define TSTEPS 1024
#define BATCH  128
#define NIN    256
#define NHID   512
#define GM     4
#define MBLK   32
#define XPSTR  528     // x row-PAIR stride in bf16 elems (1056B)
#define XBUF   8448    // elems per x buffer (16 pairs)
#define HSTR   520     // h row stride in bf16 elems (1040B)
#define HBUF   16640   // elems per h buffer (32*520)

__device__ __forceinline__ unsigned short f2bf(float f) {
  unsigned int u = __builtin_bit_cast(unsigned int, f);
  u += 0x7fffu + ((u >> 16) & 1u);
  return (unsigned short)(u >> 16);
}

__device__ __forceinline__ unsigned long long pack4(float a, float b, float c, float d) {
  return (unsigned long long)f2bf(a)
       | ((unsigned long long)f2bf(b) << 16)
       | ((unsigned long long)f2bf(c) << 32)
       | ((unsigned long long)f2bf(d) << 48);
}

__device__ __forceinline__ float sigf(float x) {
  return 1.0f / (1.0f + __expf(-x));
}
__device__ __forceinline__ float tanh_fast(float x) {
  x = fminf(fmaxf(x, -15.0f), 15.0f);
  float e = __expf(2.0f * x);
  return (e - 1.0f) / (e + 1.0f);
}

// Zero the tagged h exchange buffer: [4 groups][2 slots][4096 cells][16B] = 512KB.
// Slot0 tag=0 + zero data == valid h_0 = 0 for the t=0 poll.
__global__ void init_ws_kernel(unsigned long long* tbuf) {
  int idx = blockIdx.x * blockDim.x + threadIdx.x;
  for (int i = idx; i < 65536; i += 16384) tbuf[i] = 0ull;
}

// One-time x fp32 -> bf16 (linear layout, same [t][m][c] order).
__global__ void convert_x_kernel(const float* __restrict__ x, unsigned short* __restrict__ xbf) {
  const int N4 = TSTEPS * BATCH * NIN / 4;
  for (int i = blockIdx.x * blockDim.x + threadIdx.x; i < N4; i += gridDim.x * blockDim.x) {
    float4 f = *(const float4*)(x + (size_t)i * 4);
    *(unsigned long long*)(xbf + (size_t)i * 4) = pack4(f.x, f.y, f.z, f.w);
  }
}

#define MFMA(va, fb, acc) \
  acc = __builtin_amdgcn_mfma_f32_32x32x16_bf16(va, fb, acc, 0, 0, 0)

// DEVICE scope (sc1 only): cross-XCD coherent at the shared fabric/L3 level.
// R5-R14 used sc0 sc1 (SYSTEM scope) -> memory-class latency on every exchange RT.
#define CLOAD(cv, off) \
  asm volatile("global_load_dwordx4 %0, %1, off sc1" : "=v"(cv) : "v"(rb + (off)))

template <int USE_DMA>
__global__ __launch_bounds__(256, 1) void lstm_persistent(
    const float* __restrict__ x,            // fp32 x (MODE0 only)
    const unsigned short* __restrict__ xbf, // bf16 x (MODE1 only)
    const float* __restrict__ Wih,
    const float* __restrict__ Whh,
    const float* __restrict__ bih,
    const float* __restrict__ bhh,
    float* __restrict__ out,                // h, h, c
    char* __restrict__ tbuf)                // [4][2][4096] 16B tagged cells
{
  const int tid  = threadIdx.x;
  const int lane = tid & 63;
  const int wv   = tid >> 6;
  const int gm   = blockIdx.x & (GM - 1);
  const int gh   = blockIdx.x >> 2;
  const int m0   = gm * MBLK;
  const int hc0  = gh * 32;

  __shared__ short x_flat[3 * XBUF];
  __shared__ short h_flat[2 * HBUF];
  __shared__ float z_lds[4][MBLK][36];

  // ---------------- W fragments -> registers ----------------
  const int ncol = lane & 31;
  const int h5   = lane >> 5;
  const int arow = lane & 31;
  const int kg   = h5 * 8;
  const int gate = ncol >> 3;
  const int wrow = gate * NHID + hc0 + wv * 8 + (ncol & 7);

  short8 bfrag[48];
#pragma unroll
  for (int kb = 0; kb < 48; ++kb) {
    const float* src = (kb < 16)
        ? (Wih + (size_t)wrow * NIN  + (kb * 16 + kg))
        : (Whh + (size_t)wrow * NHID + (kb * 16 + kg - NIN));
    float4 f0 = *(const float4*)src;
    float4 f1 = *(const float4*)(src + 4);
    short8 b;
    b[0] = (short)f2bf(f0.x); b[1] = (short)f2bf(f0.y);
    b[2] = (short)f2bf(f0.z); b[3] = (short)f2bf(f0.w);
    b[4] = (short)f2bf(f1.x); b[5] = (short)f2bf(f1.y);
    b[6] = (short)f2bf(f1.z); b[7] = (short)f2bf(f1.w);
    bfrag[kb] = b;
  }
  const float bias_c = bih[wrow] + bhh[wrow];

  // gate mapping (R6/R9): thread owns (row tid>>3, cols (tid&7)*4..+3)
  const int grow = tid >> 3;
  const int c4   = (tid & 7) * 4;
  float creg[4] = {0.0f, 0.0f, 0.0f, 0.0f};

  const char* tb = tbuf + (size_t)gm * 131072;          // [slot][4096 cells]
  const int  myci = grow * 128 + (hc0 >> 2) + (tid & 7); // producer cell index

#define XLOAD(i, v) { int u = tid + 256 * (i); \
    v = *(const float4*)(xt + (size_t)(u >> 6) * NIN + (u & 63) * 4); }
#define XPACK(bb, i, v) { int u = tid + 256 * (i); int r = u >> 6; int hc = u & 63; \
    *(unsigned long long*)&x_flat[(bb) * XBUF + (r >> 1) * XPSTR + (r & 1) * NIN + hc * 4] \
        = pack4(v.x, v.y, v.z, v.w); }
#define XDMA(tt, bb) { \
    const unsigned short* gsrc = xbf + ((size_t)(tt) * BATCH + m0) * NIN; \
    short* ldst = x_flat + (bb) * XBUF; \
    _Pragma("unroll") \
    for (int j = 0; j < 4; ++j) { \
      int ck = 4 * wv + j; \
      const unsigned short* gp = gsrc + (size_t)(2 * ck + h5) * NIN + (lane & 31) * 8; \
      __builtin_amdgcn_global_load_lds((const unsigned int*)gp, \
          (unsigned int*)(ldst + ck * XPSTR), 16, 0, 0); \
    } }

  f32x16 a0, a1, a2, a3;
  float4 xv0, xv1, xv2, xv3, xv4, xv5, xv6, xv7;

  // ---------------- prologue: stage x0..x2, compute zx_0 ----------------
  if (USE_DMA) {
    XDMA(0, 0) XDMA(1, 1) XDMA(2, 2)
    asm volatile("s_waitcnt vmcnt(0)" ::: "memory");
  } else {
    { const float* xt = x + (size_t)m0 * NIN;
      XLOAD(0, xv0) XLOAD(1, xv1) XLOAD(2, xv2) XLOAD(3, xv3)
      XLOAD(4, xv4) XLOAD(5, xv5) XLOAD(6, xv6) XLOAD(7, xv7)
      XPACK(0, 0, xv0) XPACK(0, 1, xv1) XPACK(0, 2, xv2) XPACK(0, 3, xv3)
      XPACK(0, 4, xv4) XPACK(0, 5, xv5) XPACK(0, 6, xv6) XPACK(0, 7, xv7) }
    { const float* xt = x + ((size_t)BATCH + m0) * NIN;
      XLOAD(0, xv0) XLOAD(1, xv1) XLOAD(2, xv2) XLOAD(3, xv3)
      XLOAD(4, xv4) XLOAD(5, xv5) XLOAD(6, xv6) XLOAD(7, xv7)
      XPACK(1, 0, xv0) XPACK(1, 1, xv1) XPACK(1, 2, xv2) XPACK(1, 3, xv3)
      XPACK(1, 4, xv4) XPACK(1, 5, xv5) XPACK(1, 6, xv6) XPACK(1, 7, xv7) }
  }
  __syncthreads();
  a0 = (f32x16)bias_c; a1 = (f32x16)0.0f; a2 = (f32x16)0.0f; a3 = (f32x16)0.0f;
  {
    const short* xrow = x_flat + (arow >> 1) * XPSTR + (arow & 1) * NIN + kg;
#pragma unroll
    for (int kb = 0; kb < 16; kb += 4) {
      MFMA(*(const short8*)(xrow + (kb + 0) * 16), bfrag[kb + 0], a0);
      MFMA(*(const short8*)(xrow + (kb + 1) * 16), bfrag[kb + 1], a1);
      MFMA(*(const short8*)(xrow + (kb + 2) * 16), bfrag[kb + 2], a2);
      MFMA(*(const short8*)(xrow + (kb + 3) * 16), bfrag[kb + 3], a3);
    }
  }

  int tmod = 0;   // t % 3
  for (int t = 0; t < TSTEPS; ++t) {
    // -------- 1+2. tagged poll: detect and h data arrive in the SAME loads ----------
    {
      const char* rb = tb + (size_t)(t & 1) * 65536 + (size_t)tid * 16;
      const unsigned int tg = (unsigned int)t;
      uint4v c0, c1, c2, c3, c4v, c5, c6, c7, c8, c9, c10, c11, c12, c13, c14, c15;
      int ok;
      do {
        CLOAD(c0,  0 * 4096); CLOAD(c1,  1 * 4096); CLOAD(c2,  2 * 4096);
        CLOAD(c3,  3 * 4096); CLOAD(c4v, 4 * 4096); CLOAD(c5,  5 * 4096);
        CLOAD(c6,  6 * 4096); CLOAD(c7,  7 * 4096); CLOAD(c8,  8 * 4096);
        CLOAD(c9,  9 * 4096); CLOAD(c10, 10 * 4096); CLOAD(c11, 11 * 4096);
        CLOAD(c12, 12 * 4096); CLOAD(c13, 13 * 4096); CLOAD(c14, 14 * 4096);
        CLOAD(c15, 15 * 4096);
        asm volatile("s_waitcnt vmcnt(0)" ::: "memory");
        ok = (c0.z == tg) & (c1.z == tg) & (c2.z == tg) & (c3.z == tg)
           & (c4v.z == tg) & (c5.z == tg) & (c6.z == tg) & (c7.z == tg)
           & (c8.z == tg) & (c9.z == tg) & (c10.z == tg) & (c11.z == tg)
           & (c12.z == tg) & (c13.z == tg) & (c14.z == tg) & (c15.z == tg);
      } while (!__all(ok));
      __builtin_amdgcn_sched_barrier(0);
      short* hdst = h_flat + (t & 1) * HBUF;
#define HPUT(j, cv) { int ci = tid + 256 * (j); \
      *(unsigned long long*)&hdst[(ci >> 7) * HSTR + (ci & 127) * 4] = \
          (unsigned long long)cv.x | ((unsigned long long)cv.y << 32); }
      HPUT(0, c0)  HPUT(1, c1)  HPUT(2, c2)  HPUT(3, c3)
      HPUT(4, c4v) HPUT(5, c5)  HPUT(6, c6)  HPUT(7, c7)
      HPUT(8, c8)  HPUT(9, c9)  HPUT(10, c10) HPUT(11, c11)
      HPUT(12, c12) HPUT(13, c13) HPUT(14, c14) HPUT(15, c15)
#undef HPUT
    }
    __syncthreads();                       // (a)

    // -------- 3. MODE0: issue x_{t+2} register loads ---------------------------------
    if (!USE_DMA && t + 2 < TSTEPS) {
      const float* xt = x + ((size_t)(t + 2) * BATCH + m0) * NIN;
      XLOAD(0, xv0) XLOAD(1, xv1) XLOAD(2, xv2) XLOAD(3, xv3)
      XLOAD(4, xv4) XLOAD(5, xv5) XLOAD(6, xv6) XLOAD(7, xv7)
    }

    // -------- 4. 32 h-part MFMAs accumulate onto zx_t --------------------------------
    {
      const short* hrow = h_flat + (t & 1) * HBUF + arow * HSTR + kg;
#pragma unroll
      for (int kb = 0; kb < 32; kb += 4) {
        MFMA(*(const short8*)(hrow + (kb + 0) * 16), bfrag[16 + kb + 0], a0);
        MFMA(*(const short8*)(hrow + (kb + 1) * 16), bfrag[16 + kb + 1], a1);
        MFMA(*(const short8*)(hrow + (kb + 2) * 16), bfrag[16 + kb + 2], a2);
        MFMA(*(const short8*)(hrow + (kb + 3) * 16), bfrag[16 + kb + 3], a3);
      }
    }

    // -------- 5. z -> LDS, barrier (b) ----------------------------------------------
    {
      f32x16 acc = (a0 + a1) + (a2 + a3);
#pragma unroll
      for (int r = 0; r < 16; ++r) {
        int zr = (r & 3) + 8 * (r >> 2) + 4 * h5;
        z_lds[wv][zr][ncol] = acc[r];
      }
    }
    __syncthreads();                       // (b)

    // -------- 6. gates + cell update; publish via ONE tagged store -------------------
    {
      const int wz = c4 >> 3;
      const int cc = c4 & 7;
      const float* zrow = &z_lds[wz][grow][0];
      float4 vi = *(const float4*)&zrow[ 0 + cc];
      float4 vf = *(const float4*)&zrow[ 8 + cc];
      float4 vg = *(const float4*)&zrow[16 + cc];
      float4 vo = *(const float4*)&zrow[24 + cc];
      float zi[4] = {vi.x, vi.y, vi.z, vi.w};
      float zf[4] = {vf.x, vf.y, vf.z, vf.w};
      float zg[4] = {vg.x, vg.y, vg.z, vg.w};
      float zo[4] = {vo.x, vo.y, vo.z, vo.w};
      float hnv[4];
#pragma unroll
      for (int u = 0; u < 4; ++u) {
        float iv = sigf(zi[u]);
        float fv = sigf(zf[u]);
        float gv = tanh_fast(zg[u]);
        float ov = sigf(zo[u]);
        float cn = fv * creg[u] + iv * gv;
        creg[u] = cn;
        hnv[u] = ov * tanh_fast(cn);
      }
      if (t == TSTEPS - 1) {
        size_t o = (size_t)(m0 + grow) * NHID + hc0 + c4;
        float4 hq; hq.x = hnv[0]; hq.y = hnv[1]; hq.z = hnv[2]; hq.w = hnv[3];
        float4 cq; cq.x = creg[0]; cq.y = creg[1]; cq.z = creg[2]; cq.w = creg[3];
        *(float4*)&out[o]          = hq;
        *(float4*)&out[65536 + o]  = hq;
        *(float4*)&out[131072 + o] = cq;
      } else {
        unsigned long long hp = pack4(hnv[0], hnv[1], hnv[2], hnv[3]);
        uint4v sv;
        sv.x = (unsigned int)hp;
        sv.y = (unsigned int)(hp >> 32);
        sv.z = (unsigned int)(t + 1);     // tag rides WITH the data: no drain, no flag
        sv.w = 0u;
        const char* wb = tb + (size_t)((t + 1) & 1) * 65536 + (size_t)myci * 16;
        asm volatile("global_store_dwordx4 %0, %1, off sc1"
                     :: "v"(wb), "v"(sv) : "memory");
      }
    }

    if (t < TSTEPS - 1) {
      // -------- 7. refill x pipeline ------------------------------------------------
      if (USE_DMA) {
        if (t + 3 < TSTEPS) { XDMA(t + 3, tmod) }
      } else if (t + 2 < TSTEPS) {
        int pb = tmod + 2; if (pb >= 3) pb -= 3;
        XPACK(pb, 0, xv0) XPACK(pb, 1, xv1) XPACK(pb, 2, xv2) XPACK(pb, 3, xv3)
        XPACK(pb, 4, xv4) XPACK(pb, 5, xv5) XPACK(pb, 6, xv6) XPACK(pb, 7, xv7)
      }
      // -------- 8. zx_{t+1} = bias + x-part -----------------------------------------
      int nb = tmod + 1; if (nb >= 3) nb -= 3;
      a0 = (f32x16)bias_c; a1 = (f32x16)0.0f; a2 = (f32x16)0.0f; a3 = (f32x16)0.0f;
      const short* xrow = x_flat + nb * XBUF + (arow >> 1) * XPSTR + (arow & 1) * NIN + kg;
#pragma unroll
      for (int kb = 0; kb < 16; kb += 4) {
        MFMA(*(const short8*)(xrow + (kb + 0) * 16), bfrag[kb + 0], a0);
        MFMA(*(const short8*)(xrow + (kb + 1) * 16), bfrag[kb + 1], a1);
        MFMA(*(const short8*)(xrow + (kb + 2) * 16), bfrag[kb + 2], a2);
        MFMA(*(const short8*)(xrow + (kb + 3) * 16), bfrag[kb + 3], a3);
      }
    }
    tmod = tmod + 1; if (tmod >= 3) tmod = 0;
  }
#undef XLOAD
#undef XPACK
#undef XDMA
}

extern "C" void kernel_launch(void* const* d_in, const int* in_sizes, int n_in,
                              void* d_out, int out_size, void* d_ws, size_t ws_size,
                              hipStream_t stream) {
  const float* x   = (const float*)d_in[0];
  const float* Wih = (const float*)d_in[1];
  const float* Whh = (const float*)d_in[2];
  const float* bih = (const float*)d_in[3];
  const float* bhh = (const float*)d_in[4];
  float* out = (float*)d_out;

  char* tbuf = (char*)d_ws;                                            // 512 KB tagged cells
  unsigned short* xbf = (unsigned short*)((char*)d_ws + (1 << 20));    // 64 MB bf16 x

  size_t need = (size_t)(1 << 20) + (size_t)TSTEPS * BATCH * NIN * 2;
  bool dma = ws_size >= need;

  hipLaunchKernelGGL(init_ws_kernel, dim3(64), dim3(256), 0, stream,
                     (unsigned long long*)tbuf);
  if (dma) {
    hipLaunchKernelGGL(convert_x_kernel, dim3(8192), dim3(256), 0, stream, x, xbf);
    hipLaunchKernelGGL((lstm_persistent<1>), dim3(64), dim3(256), 0, stream,
                       x, xbf, Wih, Whh, bih, bhh, out, tbuf);
  } else {
    hipLaunchKernelGGL((lstm_persistent<0>), dim3(64), dim3(256), 0, stream,
                       x, xbf, Wih, Whh, bih, bhh, out, tbuf);
  }
}